// Round 9
// baseline (477.291 us; speedup 1.0000x reference)
//
#include <hip/hip_runtime.h>
#include <hip/hip_bf16.h>
#include <cstdint>

// GGNN encoder, B=4, N=1024, DIN=D=256, E=5, STEP=5. Inputs fp32 (sniffed).
// Round 9: global_load_lds (16B async DMA) staging for all internal-bf16 GEMM
// operands (m93->m97 ladder: 1.7x on this K-loop); gi = grouped-K over the 5
// part slices (ld8_sum5 deleted); gru vectorized x4.

typedef __attribute__((ext_vector_type(8))) short bf16x8;
typedef __attribute__((ext_vector_type(4))) short bf16x4;
typedef __attribute__((ext_vector_type(4))) float f32x4;

__device__ __forceinline__ float bf2f(__hip_bfloat16 x) { return __bfloat162float(x); }
__device__ __forceinline__ __hip_bfloat16 f2bf(float x) { return __float2bfloat16(x); }
__device__ __forceinline__ short f2bs(float x) {
  __hip_bfloat16 h = __float2bfloat16(x);
  return *reinterpret_cast<short*>(&h);
}
__device__ __forceinline__ float s2f(short x) {
  __hip_bfloat16 h = *reinterpret_cast<__hip_bfloat16*>(&x);
  return __bfloat162float(h);
}

// async global->LDS DMA, 16 B per lane; LDS dest = wave-uniform base + lane*16
__device__ __forceinline__ void gll16(const __hip_bfloat16* g, __hip_bfloat16* lds) {
  __builtin_amdgcn_global_load_lds(
      (const __attribute__((address_space(1))) uint32_t*)(uintptr_t)g,
      (__attribute__((address_space(3))) uint32_t*)(uint32_t)(uintptr_t)lds,
      16, 0, 0);
}

__device__ __forceinline__ bf16x8 ld8_ext(const void* base, long off, bool f32) {
  if (f32) {
    const float* p = (const float*)base + off;
    bf16x8 r;
#pragma unroll
    for (int i = 0; i < 8; ++i) r[i] = f2bs(p[i]);
    return r;
  }
  return *(const bf16x8*)((const __hip_bfloat16*)base + off);
}

// ---- dtype sniffer: flag = 1 if inputs are fp32, 0 if bf16 ----
__global__ void detect_dtype(const uint32_t* __restrict__ raw, int* __restrict__ flag) {
  __shared__ int cnt;
  if (threadIdx.x == 0) cnt = 0;
  __syncthreads();
  int c = 0;
  for (int i = threadIdx.x; i < 512; i += 256) {
    uint32_t byte = (raw[i] >> 8) & 0xFF;
    if (byte >= 0x28 && byte <= 0x40) ++c;
  }
  atomicAdd(&cnt, c);
  __syncthreads();
  if (threadIdx.x == 0) *flag = (cnt < 300) ? 1 : 0;
}

// fp32 pool: [0:256) fc_b | [256:1024) b_ih | [1024:1792) b_hh | [1792:2048)
// conv1_b | [2048:2304) conv2_b | [2304:2560) sum_e edge_b | [2560:3328) bias_gi
__global__ void prep_pool(const void* fcb, const void* bih, const void* bhh,
                          const void* c1b, const void* c2b, const void* edgeb,
                          const int* __restrict__ flag,
                          float* __restrict__ pool, float* __restrict__ ge,
                          float* __restrict__ am32) {
  const bool f32 = (*flag != 0);
  for (int t = threadIdx.x; t < 2560; t += 256) {
    const void* p; int i;
    if (t < 256)       { p = fcb;  i = t; }
    else if (t < 1024) { p = bih;  i = t - 256; }
    else if (t < 1792) { p = bhh;  i = t - 1024; }
    else if (t < 2048) { p = c1b;  i = t - 1792; }
    else if (t < 2304) { p = c2b;  i = t - 2048; }
    else {
      int k = t - 2304; float s = 0.f;
      for (int e = 0; e < 5; ++e)
        s += f32 ? ((const float*)edgeb)[e * 256 + k]
                 : bf2f(((const __hip_bfloat16*)edgeb)[e * 256 + k]);
      pool[t] = s; continue;
    }
    pool[t] = f32 ? ((const float*)p)[i] : bf2f(((const __hip_bfloat16*)p)[i]);
  }
  for (int t = threadIdx.x; t < 1024; t += 256) ge[t] = 0.f;
  for (int t = threadIdx.x; t < 4096; t += 256) am32[t] = 0.f;
}

// bias_gi[n] = b_ih[n] + sum_k sum_edge_b[k] * w_ih[n][k]   (n < 768)
__global__ void bias_gi_k(const float* __restrict__ pool,
                          const __hip_bfloat16* __restrict__ wih,
                          float* __restrict__ out) {
  const int n = blockIdx.x * 256 + threadIdx.x;
  if (n >= 768) return;
  float s = pool[256 + n];
  for (int k = 0; k < 256; ++k) s += pool[2304 + k] * bf2f(wih[n * 256 + k]);
  out[n] = s;
}

// ingest all 6 weight matrices into one internal bf16 pool
__global__ void wcvt_all(const void* fcw, const void* edw, const void* wih,
                         const void* whh, const void* c1w, const void* c2w,
                         const int* __restrict__ flag, __hip_bfloat16* __restrict__ dst) {
  const bool f32 = (*flag != 0);
  const int i = blockIdx.x * 256 + threadIdx.x;   // 0..917503
  const void* src; int off;
  if      (i < 65536)  { src = fcw; off = i; }
  else if (i < 393216) { src = edw; off = i - 65536; }
  else if (i < 589824) { src = wih; off = i - 393216; }
  else if (i < 786432) { src = whh; off = i - 589824; }
  else if (i < 851968) { src = c1w; off = i - 786432; }
  else                 { src = c2w; off = i - 851968; }
  dst[i] = f32 ? f2bf(((const float*)src)[off])
               : ((const __hip_bfloat16*)src)[off];
}

// one-time adj -> internal bf16 (20,971,520 elems), 8 elems/thread
__global__ void adj_cvt(const void* __restrict__ src, const int* __restrict__ flag,
                        __hip_bfloat16* __restrict__ dst) {
  const bool f32 = (*flag != 0);
  const long i = ((long)blockIdx.x * 256 + threadIdx.x) * 8;
  bf16x8 r;
  if (f32) {
    const float* p = (const float*)src + i;
#pragma unroll
    for (int j = 0; j < 8; ++j) r[j] = f2bs(p[j]);
  } else {
    r = *(const bf16x8*)((const __hip_bfloat16*)src + i);
  }
  *(bf16x8*)(dst + i) = r;
}

// OUT_MODE: 0=bf16 C; 1=fp32 C.  A_MODE: 0=internal bf16 (DMA), 1=external
// (flag dtype, register staging).  DUAL: z>=zSplit switches to 2nd set
// (2nd set must be internal bf16; uses ngrp2/aBatch2).
template<int OUT_MODE, bool HAS_BIAS, int A_MODE, bool DUAL>
__global__ __launch_bounds__(256)
void gemm_bt(const void* __restrict__ A, const __hip_bfloat16* __restrict__ Bt,
             const float* __restrict__ bias, void* __restrict__ Cp,
             const void* __restrict__ A2, const __hip_bfloat16* __restrict__ Bt2,
             const float* __restrict__ bias2, void* __restrict__ Cp2,
             const int* __restrict__ flag,
             int Kg, int ngrp, int lda, int ldb, int ldc,
             long aBatch, int zdivA, int zmodA,
             long bBatch, int zdivB, int zmodB,
             long cBatch, int zdivC, long aGrp, long bGrp,
             int zSplit, int ngrp2, long aBatch2)
{
  __shared__ __align__(16) __hip_bfloat16 sA[64 * 64];
  __shared__ __align__(16) __hip_bfloat16 sB[64 * 64];
  const bool af32 = (A_MODE == 1) ? (*flag != 0) : false;
  const int t = threadIdx.x;
  const int w = t >> 6;
  const int l = t & 63;
  const int m0 = blockIdx.x * 64;
  const int n0 = blockIdx.y * 64;
  int z = blockIdx.z;

  const void* Au = A; const __hip_bfloat16* Btu = Bt;
  const float* biasu = bias; void* Cpu = Cp;
  int ngrpu = ngrp; long aBatchu = aBatch;
  if (DUAL && z >= zSplit) {
    Au = A2; Btu = Bt2; biasu = bias2; Cpu = Cp2; z -= zSplit;
    ngrpu = ngrp2; aBatchu = aBatch2;
  }

  const long aOff = (long)((z / zdivA) % zmodA) * aBatchu;
  const __hip_bfloat16* Bb = Btu + (long)((z / zdivB) % zmodB) * bBatch;

  // staging: 16B chunk p -> LDS(row=p>>3, slot=p&7); slot s of row r holds
  // data chunk s ^ (r&7). Swizzle applied on GLOBAL address; LDS dest is
  // base + lane*16 (wave-uniform base) as global_load_lds requires.
  const int p0 = t, p1 = t + 256;
  const int sr0 = p0 >> 3, sc0 = (p0 & 7) ^ (sr0 & 7);
  const int sr1 = p1 >> 3, sc1 = (p1 & 7) ^ (sr1 & 7);

  f32x4 acc[4];
#pragma unroll
  for (int i = 0; i < 4; ++i) acc[i] = (f32x4){0.f, 0.f, 0.f, 0.f};

  const int mrow = w * 16 + (l & 15);
  const int quad = l >> 4;

  for (int g = 0; g < ngrpu; ++g) {
    const long aG = aOff + (long)g * aGrp;
    const __hip_bfloat16* Bg = Bb + (long)g * bGrp;
    for (int k0 = 0; k0 < Kg; k0 += 64) {
      bf16x8 a0r, a1r;
      if (A_MODE == 1) {
        a0r = ld8_ext(Au, aG + (long)(m0 + sr0) * lda + (k0 + sc0 * 8), af32);
        a1r = ld8_ext(Au, aG + (long)(m0 + sr1) * lda + (k0 + sc1 * 8), af32);
      }
      __syncthreads();   // previous tile fully consumed
      if (A_MODE == 0) {
        const __hip_bfloat16* Ab = (const __hip_bfloat16*)Au;
        gll16(Ab + aG + (long)(m0 + sr0) * lda + (k0 + sc0 * 8), sA + p0 * 8);
        gll16(Ab + aG + (long)(m0 + sr1) * lda + (k0 + sc1 * 8), sA + p1 * 8);
      } else {
        *(bf16x8*)(sA + p0 * 8) = a0r;
        *(bf16x8*)(sA + p1 * 8) = a1r;
      }
      gll16(Bg + (long)(n0 + sr0) * ldb + (k0 + sc0 * 8), sB + p0 * 8);
      gll16(Bg + (long)(n0 + sr1) * ldb + (k0 + sc1 * 8), sB + p1 * 8);
      __syncthreads();   // drains vmcnt (DMA) + lgkm (ds_write)
#pragma unroll
      for (int ks = 0; ks < 2; ++ks) {
        const int cg = ks * 4 + quad;
        bf16x8 af = *(const bf16x8*)(sA + mrow * 64 + ((cg ^ (mrow & 7)) * 8));
#pragma unroll
        for (int t4 = 0; t4 < 4; ++t4) {
          const int nrow = t4 * 16 + (l & 15);
          bf16x8 bfr = *(const bf16x8*)(sB + nrow * 64 + ((cg ^ (nrow & 7)) * 8));
          acc[t4] = __builtin_amdgcn_mfma_f32_16x16x32_bf16(af, bfr, acc[t4], 0, 0, 0);
        }
      }
    }
  }

  // C/D layout: col = lane&15, row = (lane>>4)*4 + reg
  const long cOff = (long)(z / zdivC) * cBatch;
#pragma unroll
  for (int t4 = 0; t4 < 4; ++t4) {
    const int n = n0 + t4 * 16 + (l & 15);
    float bv = 0.f;
    if (HAS_BIAS) bv = biasu[n];
#pragma unroll
    for (int r = 0; r < 4; ++r) {
      const int m = m0 + w * 16 + quad * 4 + r;
      const float v = acc[t4][r] + bv;
      if (OUT_MODE == 0)
        ((__hip_bfloat16*)Cpu)[cOff + (long)m * ldc + n] = f2bf(v);
      else
        ((float*)Cpu)[cOff + (long)m * ldc + n] = v;
    }
  }
}

// torch GRUCell gates [r,z,n]; x4 vectorized; final step writes node_states
__global__ void gru_gate(const __hip_bfloat16* __restrict__ gi,
                         const __hip_bfloat16* __restrict__ gh,
                         __hip_bfloat16* __restrict__ hbf,
                         void* __restrict__ ns_out, const int* __restrict__ flag)
{
  const int m = blockIdx.x * 4 + (threadIdx.x >> 6);
  const int c = (threadIdx.x & 63) * 4;
  const long gb = (long)m * 768 + c;
  const bf16x4 vir = *(const bf16x4*)(gi + gb);
  const bf16x4 viz = *(const bf16x4*)(gi + gb + 256);
  const bf16x4 vin = *(const bf16x4*)(gi + gb + 512);
  const bf16x4 vhr = *(const bf16x4*)(gh + gb);
  const bf16x4 vhz = *(const bf16x4*)(gh + gb + 256);
  const bf16x4 vhn = *(const bf16x4*)(gh + gb + 512);
  const long hidx = (long)m * 256 + c;
  const bf16x4 vh = *(const bf16x4*)(hbf + hidx);
  bf16x4 vout;
  float f4[4];
#pragma unroll
  for (int j = 0; j < 4; ++j) {
    const float r = 1.f / (1.f + __expf(-(s2f(vir[j]) + s2f(vhr[j]))));
    const float zz = 1.f / (1.f + __expf(-(s2f(viz[j]) + s2f(vhz[j]))));
    const float nn = tanhf(s2f(vin[j]) + r * s2f(vhn[j]));
    const float hnew = (1.f - zz) * nn + zz * s2f(vh[j]);
    vout[j] = f2bs(hnew);
    f4[j] = hnew;
  }
  *(bf16x4*)(hbf + hidx) = vout;
  if (ns_out) {
    if (*flag) *(float4*)((float*)ns_out + 1024 + hidx) = *(const float4*)f4;
    else       *(bf16x4*)((__hip_bfloat16*)ns_out + 1024 + hidx) = vout;
  }
}

// fused output epilogue: attl & fetl via MFMA (DMA staging), sigmoid/tanh,
// ge + attn row-sum reductions via LDS + global atomics.
__global__ __launch_bounds__(256)
void conv_fused(const __hip_bfloat16* __restrict__ hbf,
                const __hip_bfloat16* __restrict__ c1w,
                const __hip_bfloat16* __restrict__ c2w,
                const float* __restrict__ pool,
                float* __restrict__ geg, float* __restrict__ am32)
{
  __shared__ __align__(16) __hip_bfloat16 sA[64 * 64];
  __shared__ __align__(16) __hip_bfloat16 sB1[64 * 64];
  __shared__ __align__(16) __hip_bfloat16 sB2[64 * 64];
  __shared__ float sge[64];
  __shared__ float sam[64];
  const int t = threadIdx.x, w = t >> 6, l = t & 63;
  const int m0 = blockIdx.x * 64, n0 = blockIdx.y * 64;
  if (t < 64) { sge[t] = 0.f; sam[t] = 0.f; }
  const int p0 = t, p1 = t + 256;
  const int sr0 = p0 >> 3, sc0 = (p0 & 7) ^ (sr0 & 7);
  const int sr1 = p1 >> 3, sc1 = (p1 & 7) ^ (sr1 & 7);
  f32x4 a1[4], a2[4];
#pragma unroll
  for (int i = 0; i < 4; ++i) { a1[i] = (f32x4){0,0,0,0}; a2[i] = (f32x4){0,0,0,0}; }
  const int mrow = w * 16 + (l & 15);
  const int quad = l >> 4;
  for (int k0 = 0; k0 < 256; k0 += 64) {
    __syncthreads();
    gll16(hbf + (long)(m0 + sr0) * 256 + (k0 + sc0 * 8), sA + p0 * 8);
    gll16(hbf + (long)(m0 + sr1) * 256 + (k0 + sc1 * 8), sA + p1 * 8);
    gll16(c1w + (long)(n0 + sr0) * 256 + (k0 + sc0 * 8), sB1 + p0 * 8);
    gll16(c1w + (long)(n0 + sr1) * 256 + (k0 + sc1 * 8), sB1 + p1 * 8);
    gll16(c2w + (long)(n0 + sr0) * 256 + (k0 + sc0 * 8), sB2 + p0 * 8);
    gll16(c2w + (long)(n0 + sr1) * 256 + (k0 + sc1 * 8), sB2 + p1 * 8);
    __syncthreads();
#pragma unroll
    for (int ks = 0; ks < 2; ++ks) {
      const int cg = ks * 4 + quad;
      bf16x8 af = *(const bf16x8*)(sA + mrow * 64 + ((cg ^ (mrow & 7)) * 8));
#pragma unroll
      for (int t4 = 0; t4 < 4; ++t4) {
        const int nrow = t4 * 16 + (l & 15);
        bf16x8 b1f = *(const bf16x8*)(sB1 + nrow * 64 + ((cg ^ (nrow & 7)) * 8));
        bf16x8 b2f = *(const bf16x8*)(sB2 + nrow * 64 + ((cg ^ (nrow & 7)) * 8));
        a1[t4] = __builtin_amdgcn_mfma_f32_16x16x32_bf16(af, b1f, a1[t4], 0, 0, 0);
        a2[t4] = __builtin_amdgcn_mfma_f32_16x16x32_bf16(af, b2f, a2[t4], 0, 0, 0);
      }
    }
  }
  float asum[4] = {0.f, 0.f, 0.f, 0.f};
#pragma unroll
  for (int t4 = 0; t4 < 4; ++t4) {
    const int n = n0 + t4 * 16 + (l & 15);
    const float bb1 = pool[1792 + n], bb2 = pool[2048 + n];
    float g = 0.f;
#pragma unroll
    for (int r = 0; r < 4; ++r) {
      const float av = 1.f / (1.f + __expf(-(a1[t4][r] + bb1)));
      const float fv = tanhf(a2[t4][r] + bb2);
      g += av * fv;
      asum[r] += av;
    }
    atomicAdd(&sge[t4 * 16 + (l & 15)], g);
  }
#pragma unroll
  for (int r = 0; r < 4; ++r) atomicAdd(&sam[w * 16 + quad * 4 + r], asum[r]);
  __syncthreads();
  if (t < 64) atomicAdd(&geg[(m0 >> 10) * 256 + n0 + t], sge[t]);
  else if (t < 128) atomicAdd(&am32[m0 + (t - 64)], sam[t - 64]);
}

__global__ void finish_out(const float* __restrict__ ge, const float* __restrict__ am32,
                           void* __restrict__ dout, const int* __restrict__ flag)
{
  const int t = blockIdx.x * 256 + threadIdx.x;   // 0..5119
  const bool f32 = (*flag != 0);
  if (t < 1024) {
    if (f32) ((float*)dout)[t] = ge[t];
    else     ((__hip_bfloat16*)dout)[t] = f2bf(ge[t]);
  } else {
    const float v = am32[t - 1024] * (1.f / 256.f);
    if (f32) ((float*)dout)[1049600 + t - 1024] = v;
    else     ((__hip_bfloat16*)dout)[1049600 + t - 1024] = f2bf(v);
  }
}

extern "C" void kernel_launch(void* const* d_in, const int* in_sizes, int n_in,
                              void* d_out, int out_size, void* d_ws, size_t ws_size,
                              hipStream_t stream) {
  (void)in_sizes; (void)n_in; (void)out_size;
  const void* node_f = d_in[0];
  const void* adj    = d_in[1];
  const void* fc_w   = d_in[2];
  const void* fc_b   = d_in[3];
  const void* edge_w = d_in[4];
  const void* edge_b = d_in[5];
  const void* w_ih   = d_in[6];
  const void* w_hh   = d_in[7];
  const void* b_ih   = d_in[8];
  const void* b_hh   = d_in[9];
  const void* c1w    = d_in[10];
  const void* c1b    = d_in[11];
  const void* c2w    = d_in[12];
  const void* c2b    = d_in[13];

  // ws: [0,4) flag | [256,13568) pool | [14336,18432) ge | [18432,34816) am32
  // [34816,..) wbf 1.75M | [1869824,..) hbf 2M
  // S=ws+3966976: heT [0,10M) | part [10M,20M) | gi [20M,26M) | gh [26M,32M)
  // adjb @ ws+40MiB (40 MiB). ws measured ~320 MiB (fill profile).
  char* ws = (char*)d_ws;
  const size_t MB = (size_t)1 << 20;
  int*            flag = (int*)(ws);
  float*          bp   = (float*)(ws + 256);
  float*          ge   = (float*)(ws + 14336);
  float*          am32 = (float*)(ws + 18432);
  __hip_bfloat16* wbf  = (__hip_bfloat16*)(ws + 34816);
  __hip_bfloat16* hbf  = (__hip_bfloat16*)(ws + 1869824);
  char*           S    = ws + 3966976;
  __hip_bfloat16* heT  = (__hip_bfloat16*)(S);
  __hip_bfloat16* part = (__hip_bfloat16*)(S + 10 * MB);
  __hip_bfloat16* gi   = (__hip_bfloat16*)(S + 20 * MB);
  __hip_bfloat16* gh   = (__hip_bfloat16*)(S + 26 * MB);
  __hip_bfloat16* adjb = (__hip_bfloat16*)(ws + 40 * MB);

  const bool has_split = ws_size >= 38 * MB;
  const bool has_adjb  = ws_size >= 81 * MB;

  detect_dtype<<<1, 256, 0, stream>>>((const uint32_t*)adj, flag);
  prep_pool<<<1, 256, 0, stream>>>(fc_b, b_ih, b_hh, c1b, c2b, edge_b, flag, bp, ge, am32);
  wcvt_all<<<3584, 256, 0, stream>>>(fc_w, edge_w, w_ih, w_hh, c1w, c2w, flag, wbf);
  bias_gi_k<<<3, 256, 0, stream>>>(bp, wbf + 393216, bp + 2560);
  if (has_adjb) adj_cvt<<<10240, 256, 0, stream>>>(adj, flag, adjb);

  // h = X @ fc_w^T + fc_b   (A external -> register staging)
  gemm_bt<0, true, 1, false><<<dim3(64, 4, 1), 256, 0, stream>>>(
      node_f, wbf + 0, bp + 0, hbf, nullptr, nullptr, nullptr, nullptr, flag,
      256, 1, 256, 256, 256, 0, 1, 1, 0, 1, 1, 0, 1, 0, 0, 0, 1, 0);

  for (int s = 0; s < 5; ++s) {
    // heT[b,e][d][node] = edge_w[e] @ h[b]^T   (all internal -> full DMA)
    gemm_bt<0, false, 0, false><<<dim3(4, 16, 20), 256, 0, stream>>>(
        wbf + 65536, hbf, nullptr, heT, nullptr, nullptr, nullptr, nullptr, flag,
        256, 1, 256, 256, 1024,
        65536, 1, 5, 262144, 5, 4,
        262144, 1, 0, 0, 0, 1, 0);
    if (has_split && has_adjb) {
      // part[b,e] = adj[b,e] @ he[b,e]
      gemm_bt<0, false, 0, false><<<dim3(16, 4, 20), 256, 0, stream>>>(
          adjb, heT, nullptr, part, nullptr, nullptr, nullptr, nullptr, flag,
          1024, 1, 1024, 1024, 256,
          1048576, 1, 20, 262144, 1, 20,
          262144, 1, 0, 0, 0, 1, 0);
      // gi[b] = sum_e part[b,e] @ w_ih^T + bias_gi   (grouped-K, ngrp=5)
      // gh[b] = h[b] @ w_hh^T + b_hh                 (dual 2nd set, ngrp2=1)
      gemm_bt<0, true, 0, true><<<dim3(16, 12, 8), 256, 0, stream>>>(
          part, wbf + 393216, bp + 2560, gi,
          hbf,  wbf + 589824, bp + 1024, gh, flag,
          256, 5, 256, 256, 768,
          1310720, 1, 4, 0, 1, 1,
          786432, 1, 262144, 0, 4, 1, 262144);
    } else if (has_split) {
      gemm_bt<0, false, 1, false><<<dim3(16, 4, 20), 256, 0, stream>>>(
          adj, heT, nullptr, part, nullptr, nullptr, nullptr, nullptr, flag,
          1024, 1, 1024, 1024, 256,
          1048576, 1, 20, 262144, 1, 20,
          262144, 1, 0, 0, 0, 1, 0);
      gemm_bt<0, true, 0, true><<<dim3(16, 12, 8), 256, 0, stream>>>(
          part, wbf + 393216, bp + 2560, gi,
          hbf,  wbf + 589824, bp + 1024, gh, flag,
          256, 5, 256, 256, 768,
          1310720, 1, 4, 0, 1, 1,
          786432, 1, 262144, 0, 4, 1, 262144);
    } else {
      // fallback: grouped-K acc (incl. sum_edge_b) into part region
      gemm_bt<0, true, 1, false><<<dim3(16, 4, 4), 256, 0, stream>>>(
          adj, heT, bp + 2304, part, nullptr, nullptr, nullptr, nullptr, flag,
          1024, 5, 1024, 1024, 256,
          (long)5 * 1048576, 1, 4, (long)5 * 262144, 1, 4,
          262144, 1, 1048576, 262144, 0, 1, 0);
      gemm_bt<0, true, 0, true><<<dim3(64, 12, 2), 256, 0, stream>>>(
          part, wbf + 393216, bp + 256, gi,
          hbf,  wbf + 589824, bp + 1024, gh, flag,
          256, 1, 256, 256, 768, 0, 1, 1, 0, 1, 1, 0, 1, 0, 0, 1, 1, 0);
    }
    gru_gate<<<1024, 256, 0, stream>>>(gi, gh, hbf,
                                       (s == 4) ? d_out : nullptr, flag);
  }

  conv_fused<<<dim3(64, 4), 256, 0, stream>>>(hbf, wbf + 786432, wbf + 851968,
                                              bp, ge, am32);
  finish_out<<<20, 256, 0, stream>>>(ge, am32, d_out, flag);
}